// Round 3
// baseline (153.541 us; speedup 1.0000x reference)
//
#include <hip/hip_runtime.h>
#include <math.h>

#define B 128
#define N 2048
#define D 256
#define K 64
#define CH 16          // chunks per batch in main kernel
#define RPB (N / CH)   // rows per block = 128

// ---------------- workspace layout (in floats) ----------------
#define OFF_V       0                          // B*D = 32768
#define OFF_C2      (OFF_V + B * D)            // B
#define OFF_CNT     (OFF_C2 + B)               // B
#define OFF_SCORES  (OFF_CNT + B)              // B*N = 262144
#define OFF_PART    (OFF_SCORES + B * N)       // B*CH*D = 524288
#define OFF_MODE    (OFF_PART + B * CH * D)    // 1 int

// ---------------- output layout (in floats) ----------------
#define O_TOK   0                      // B*K*D = 2097152
#define O_MASK  (O_TOK + B * K * D)    // B*K
#define O_IDX   (O_MASK + B * K)       // B*K
#define O_IMP   (O_IDX + B * K)        // B*K
#define O_GLOB  (O_IMP + B * K)        // B*D

__device__ __forceinline__ bool mask_at(const void* p, int mode, int i) {
    if (mode == 1) return ((const unsigned char*)p)[i] != 0;
    if (mode == 2) return ((const float*)p)[i] != 0.0f;
    return ((const int*)p)[i] != 0;
}

// Per-batch: mode-detect; q = ego@Wq^T + bq (row-per-wave float4);
// v = (q^T Wk)/16 + Ws; c2 = (q.bk)/16 + bs; cnt = sum(mask).
__global__ __launch_bounds__(256) void prep_kernel(
        const float* __restrict__ latent, const void* __restrict__ maskp,
        const float* __restrict__ Wq, const float* __restrict__ bq,
        const float* __restrict__ Wk, const float* __restrict__ bk,
        const float* __restrict__ Ws, const float* __restrict__ bs,
        float* __restrict__ v, float* __restrict__ c2, float* __restrict__ cnt,
        int* __restrict__ modep) {
    int b = blockIdx.x, t = threadIdx.x, w = t >> 6, l = t & 63;
    __shared__ float ego[D];
    __shared__ float q[D];
    __shared__ int smode;
    // dtype probe of token_mask (wave 0 scans first 4KB; safe for any dtype)
    if (w == 0) {
        const unsigned int* mw = (const unsigned int*)maskp;
        bool isF = false, hasHigh = false;
        for (int i = 0; i < 16; ++i) {
            unsigned int x = mw[l * 16 + i];
            if (x == 0x3F800000u) isF = true;
            if (x & 0xFFFFFF00u) hasHigh = true;
        }
        unsigned long long bf = __ballot(isF);
        unsigned long long bh = __ballot(hasHigh);
        if (l == 0) smode = bf ? 2 : (bh ? 1 : 0);
    }
    ego[t] = latent[(size_t)b * N * D + t];
    __syncthreads();
    int mode = smode;
    if (b == 0 && t == 0) *modep = mode;

    // q[r] = Wq[r,:] . ego + bq[r]  -- coalesced float4 row reads, shfl reduce
    float4 e4 = ((const float4*)ego)[l];
    for (int r0 = 0; r0 < 64; ++r0) {
        int r = w * 64 + r0;
        float4 x = ((const float4*)(Wq + (size_t)r * D))[l];
        float p = x.x * e4.x;
        p = fmaf(x.y, e4.y, p);
        p = fmaf(x.z, e4.z, p);
        p = fmaf(x.w, e4.w, p);
        #pragma unroll
        for (int m = 32; m >= 1; m >>= 1) p += __shfl_xor(p, m, 64);
        if (l == 0) q[r] = p + bq[r];
    }
    __syncthreads();

    // v[t] = (sum_e q[e]*Wk[e,t])/16 + Ws[t]  -- coalesced column sweep
    float a2 = 0.f;
    #pragma unroll 8
    for (int e = 0; e < D; ++e) a2 = fmaf(q[e], Wk[(size_t)e * D + t], a2);
    v[b * D + t] = a2 * 0.0625f + Ws[t];

    if (t < 64) {
        float p = 0.f;
        for (int j = 0; j < 4; ++j) { int e = t + 64 * j; p = fmaf(q[e], bk[e], p); }
        #pragma unroll
        for (int m = 32; m >= 1; m >>= 1) p += __shfl_xor(p, m, 64);
        if (t == 0) c2[b] = p * 0.0625f + bs[0];
    }
    int local = 0;
    for (int i = 0; i < N / D; ++i) local += mask_at(maskp, mode, b * N + t + D * i) ? 1 : 0;
    __shared__ int ctot;
    if (t == 0) ctot = 0;
    __syncthreads();
    atomicAdd(&ctot, local);
    __syncthreads();
    if (t == 0) cnt[b] = (float)ctot;
}

// Streaming pass: scores (masked) + partial column sums for global_latent.
__global__ __launch_bounds__(256) void main_kernel(
        const float* __restrict__ latent, const void* __restrict__ maskp,
        const int* __restrict__ modep,
        const float* __restrict__ v, const float* __restrict__ c2,
        float* __restrict__ scores, float* __restrict__ partials) {
    int b = blockIdx.y, ch = blockIdx.x;
    int t = threadIdx.x, w = t >> 6, l = t & 63;
    int mode = *modep;
    float4 vv = ((const float4*)(v + b * D))[l];
    float c2b = c2[b];
    float ax = 0.f, ay = 0.f, az = 0.f, aw = 0.f;
    int n0 = ch * RPB + w * (RPB / 4);
    const float4* lat4 = (const float4*)(latent + (size_t)b * N * D);
    for (int i = 0; i < RPB / 4; ++i) {
        int n = n0 + i;
        float4 x = lat4[(size_t)n * (D / 4) + l];
        float p = x.x * vv.x;
        p = fmaf(x.y, vv.y, p);
        p = fmaf(x.z, vv.z, p);
        p = fmaf(x.w, vv.w, p);
        #pragma unroll
        for (int m = 32; m >= 1; m >>= 1) p += __shfl_xor(p, m, 64);
        bool msk = mask_at(maskp, mode, b * N + n);
        if (l == 0) scores[(size_t)b * N + n] = msk ? (p + c2b) : -INFINITY;
        if (msk) { ax += x.x; ay += x.y; az += x.z; aw += x.w; }
    }
    __shared__ float red[4][D];
    red[w][l * 4 + 0] = ax; red[w][l * 4 + 1] = ay;
    red[w][l * 4 + 2] = az; red[w][l * 4 + 3] = aw;
    __syncthreads();
    float s = red[0][t] + red[1][t] + red[2][t] + red[3][t];
    partials[((size_t)b * CH + ch) * D + t] = s;
}

// Fused epilogue per batch: radix-select top-K -> bitonic sort (jax ties) ->
// mask/softmax/index writes -> token gather -> global_latent finalize.
__global__ __launch_bounds__(256) void epilogue_kernel(
        const float* __restrict__ scores, const void* __restrict__ maskp,
        const int* __restrict__ modep, const float* __restrict__ latent,
        const float* __restrict__ partials, const float* __restrict__ cnt,
        float* __restrict__ out_mask, float* __restrict__ out_idx,
        float* __restrict__ out_imp, float* __restrict__ out_tok,
        float* __restrict__ out_glob) {
    int b = blockIdx.x, t = threadIdx.x, w = t >> 6, l = t & 63;
    __shared__ unsigned int keys[N];
    __shared__ unsigned int hist[256];
    __shared__ int pgA[256], peA[256];
    __shared__ unsigned int selu[K];
    __shared__ int seliA[K];
    __shared__ int sortedIdx[K];
    __shared__ unsigned int s_byte;
    __shared__ int s_kneed;

    // load + order-preserving float->uint map
    for (int i = 0; i < N / 256; ++i) {
        int pos = t + 256 * i;
        unsigned int fu = __float_as_uint(scores[(size_t)b * N + pos]);
        keys[pos] = (fu & 0x80000000u) ? ~fu : (fu | 0x80000000u);
    }
    __syncthreads();

    // 4-pass radix select: find K-th largest key T and tie budget kneed
    unsigned int prefixKey = 0;
    int kneed = K;
    for (int shift = 24; shift >= 0; shift -= 8) {
        hist[t] = 0;
        __syncthreads();
        for (int i = 0; i < N / 256; ++i) {
            unsigned int u = keys[t * (N / 256) + i];
            bool match = (shift == 24) || ((u >> (shift + 8)) == (prefixKey >> (shift + 8)));
            if (match) atomicAdd(&hist[(u >> shift) & 0xFFu], 1u);
        }
        __syncthreads();
        if (t == 0) {
            int acc = 0, bsel = 0;
            for (int bb = 255; bb >= 0; --bb) {
                int h = (int)hist[bb];
                if (acc + h >= kneed) { bsel = bb; break; }
                acc += h;
            }
            s_byte = (unsigned int)bsel;
            s_kneed = kneed - acc;
        }
        __syncthreads();
        prefixKey |= (s_byte << shift);
        kneed = s_kneed;
        __syncthreads();
    }
    unsigned int T = prefixKey;

    // per-thread counts over contiguous chunk (index order preserved)
    int cGT = 0, cEQ = 0;
    for (int i = 0; i < N / 256; ++i) {
        unsigned int u = keys[t * (N / 256) + i];
        cGT += (u > T);
        cEQ += (u == T);
    }
    pgA[t] = cGT; peA[t] = cEQ;
    __syncthreads();
    for (int off = 1; off < 256; off <<= 1) {
        int a = (t >= off) ? pgA[t - off] : 0;
        int e = (t >= off) ? peA[t - off] : 0;
        __syncthreads();
        pgA[t] += a; peA[t] += e;
        __syncthreads();
    }
    int totGT = pgA[255];
    int pg = pgA[t] - cGT;
    int pe = peA[t] - cEQ;
    for (int i = 0; i < N / 256; ++i) {
        int pos = t * (N / 256) + i;
        unsigned int u = keys[pos];
        if (u > T) {
            selu[pg] = u; seliA[pg] = pos; ++pg;
        } else if (u == T) {
            if (pe < kneed) { selu[totGT + pe] = u; seliA[totGT + pe] = pos; }
            ++pe;
        }
    }
    __syncthreads();

    if (t < K) {
        unsigned int u = selu[t];
        int pos = seliA[t];
        // bitonic sort 64 pairs across wave 0, descending by (u, then -pos)
        #pragma unroll
        for (int k2 = 2; k2 <= 64; k2 <<= 1) {
            #pragma unroll
            for (int j = k2 >> 1; j >= 1; j >>= 1) {
                unsigned int ou = __shfl_xor(u, j, 64);
                int opos = __shfl_xor(pos, j, 64);
                bool lower = (t & j) == 0;
                bool descB = (t & k2) == 0;
                bool otherGreater = (ou > u) || (ou == u && opos < pos);
                if (otherGreater == (lower == descB)) { u = ou; pos = opos; }
            }
        }
        unsigned int fu = (u & 0x80000000u) ? (u ^ 0x80000000u) : ~u;
        float selv = __uint_as_float(fu);

        int mode = *modep;
        bool m = mask_at(maskp, mode, b * N + pos);
        float x = m ? selv : -1e9f;
        float mx = x;
        #pragma unroll
        for (int mm = 1; mm <= 32; mm <<= 1) mx = fmaxf(mx, __shfl_xor(mx, mm, 64));
        float e = expf(x - mx);
        float sm = e;
        #pragma unroll
        for (int mm = 1; mm <= 32; mm <<= 1) sm += __shfl_xor(sm, mm, 64);
        out_idx[b * K + t] = (float)pos;
        out_mask[b * K + t] = m ? 1.f : 0.f;
        out_imp[b * K + t] = e / sm;
        sortedIdx[t] = pos;
    }
    __syncthreads();

    // gather selected tokens (sorted order), 4 waves x 16 rows, float4 rows
    for (int r = w; r < K; r += 4) {
        int idx = sortedIdx[r];
        float4 x = ((const float4*)(latent + ((size_t)b * N + idx) * D))[l];
        ((float4*)(out_tok + ((size_t)b * K + r) * D))[l] = x;
    }
    // global_latent finalize
    float s = 0.f;
    for (int ch = 0; ch < CH; ++ch) s += partials[((size_t)b * CH + ch) * D + t];
    out_glob[b * D + t] = s / cnt[b];
}

extern "C" void kernel_launch(void* const* d_in, const int* in_sizes, int n_in,
                              void* d_out, int out_size, void* d_ws, size_t ws_size,
                              hipStream_t stream) {
    const float* latent = (const float*)d_in[0];
    const void*  maskp  = d_in[1];
    const float* Wq = (const float*)d_in[2];
    const float* bq = (const float*)d_in[3];
    const float* Wk = (const float*)d_in[4];
    const float* bk = (const float*)d_in[5];
    const float* Ws = (const float*)d_in[6];
    const float* bs = (const float*)d_in[7];

    float* ws = (float*)d_ws;
    float* v      = ws + OFF_V;
    float* c2     = ws + OFF_C2;
    float* cnt    = ws + OFF_CNT;
    float* scores = ws + OFF_SCORES;
    float* part   = ws + OFF_PART;
    int*   modep  = (int*)(ws + OFF_MODE);
    float* out = (float*)d_out;

    hipLaunchKernelGGL(prep_kernel, dim3(B), dim3(256), 0, stream,
                       latent, maskp, Wq, bq, Wk, bk, Ws, bs, v, c2, cnt, modep);
    hipLaunchKernelGGL(main_kernel, dim3(CH, B), dim3(256), 0, stream,
                       latent, maskp, modep, v, c2, scores, part);
    hipLaunchKernelGGL(epilogue_kernel, dim3(B), dim3(256), 0, stream,
                       scores, maskp, modep, latent, part, cnt,
                       out + O_MASK, out + O_IDX, out + O_IMP, out + O_TOK, out + O_GLOB);
}

// Round 4
// 119.075 us; speedup vs baseline: 1.2894x; 1.2894x over previous
//
#include <hip/hip_runtime.h>
#include <math.h>

#define B 128
#define N 2048
#define D 256
#define K 64
#define CH 16          // chunks per batch in main kernel
#define RPB (N / CH)   // rows per block = 128

// ---------------- workspace layout (in floats) ----------------
#define OFF_V       0                          // B*D = 32768
#define OFF_C2      (OFF_V + B * D)            // B
#define OFF_CNT     (OFF_C2 + B)               // B
#define OFF_SCORES  (OFF_CNT + B)              // B*N = 262144
#define OFF_PART    (OFF_SCORES + B * N)       // B*CH*D = 524288
#define OFF_MODE    (OFF_PART + B * CH * D)    // 1 int

// ---------------- output layout (in floats) ----------------
#define O_TOK   0                      // B*K*D = 2097152
#define O_MASK  (O_TOK + B * K * D)    // B*K
#define O_IDX   (O_MASK + B * K)       // B*K
#define O_IMP   (O_IDX + B * K)        // B*K
#define O_GLOB  (O_IMP + B * K)        // B*D

__device__ __forceinline__ bool mask_at(const void* p, int mode, int i) {
    if (mode == 1) return ((const unsigned char*)p)[i] != 0;
    if (mode == 2) return ((const float*)p)[i] != 0.0f;
    return ((const int*)p)[i] != 0;
}

// in-wave inclusive scan (64 lanes)
__device__ __forceinline__ int wave_iscan(int x, int l) {
    #pragma unroll
    for (int d = 1; d < 64; d <<= 1) {
        int y = __shfl_up(x, d, 64);
        if (l >= d) x += y;
    }
    return x;
}

// Per-batch: mode-detect; q = ego@Wq^T + bq (row-per-wave float4);
// v = (q^T Wk)/16 + Ws; c2 = (q.bk)/16 + bs; cnt = sum(mask).
__global__ __launch_bounds__(256) void prep_kernel(
        const float* __restrict__ latent, const void* __restrict__ maskp,
        const float* __restrict__ Wq, const float* __restrict__ bq,
        const float* __restrict__ Wk, const float* __restrict__ bk,
        const float* __restrict__ Ws, const float* __restrict__ bs,
        float* __restrict__ v, float* __restrict__ c2, float* __restrict__ cnt,
        int* __restrict__ modep) {
    int b = blockIdx.x, t = threadIdx.x, w = t >> 6, l = t & 63;
    __shared__ float ego[D];
    __shared__ float q[D];
    __shared__ int smode;
    if (w == 0) {
        const unsigned int* mw = (const unsigned int*)maskp;
        bool isF = false, hasHigh = false;
        for (int i = 0; i < 16; ++i) {
            unsigned int x = mw[l * 16 + i];
            if (x == 0x3F800000u) isF = true;
            if (x & 0xFFFFFF00u) hasHigh = true;
        }
        unsigned long long bf = __ballot(isF);
        unsigned long long bh = __ballot(hasHigh);
        if (l == 0) smode = bf ? 2 : (bh ? 1 : 0);
    }
    ego[t] = latent[(size_t)b * N * D + t];
    __syncthreads();
    int mode = smode;
    if (b == 0 && t == 0) *modep = mode;

    float4 e4 = ((const float4*)ego)[l];
    for (int r0 = 0; r0 < 64; ++r0) {
        int r = w * 64 + r0;
        float4 x = ((const float4*)(Wq + (size_t)r * D))[l];
        float p = x.x * e4.x;
        p = fmaf(x.y, e4.y, p);
        p = fmaf(x.z, e4.z, p);
        p = fmaf(x.w, e4.w, p);
        #pragma unroll
        for (int m = 32; m >= 1; m >>= 1) p += __shfl_xor(p, m, 64);
        if (l == 0) q[r] = p + bq[r];
    }
    __syncthreads();

    float a2 = 0.f;
    #pragma unroll 8
    for (int e = 0; e < D; ++e) a2 = fmaf(q[e], Wk[(size_t)e * D + t], a2);
    v[b * D + t] = a2 * 0.0625f + Ws[t];

    if (t < 64) {
        float p = 0.f;
        for (int j = 0; j < 4; ++j) { int e = t + 64 * j; p = fmaf(q[e], bk[e], p); }
        #pragma unroll
        for (int m = 32; m >= 1; m >>= 1) p += __shfl_xor(p, m, 64);
        if (t == 0) c2[b] = p * 0.0625f + bs[0];
    }
    int local = 0;
    for (int i = 0; i < N / D; ++i) local += mask_at(maskp, mode, b * N + t + D * i) ? 1 : 0;
    __shared__ int ctot;
    if (t == 0) ctot = 0;
    __syncthreads();
    atomicAdd(&ctot, local);
    __syncthreads();
    if (t == 0) cnt[b] = (float)ctot;
}

// Streaming pass: scores (masked) + partial column sums for global_latent.
__global__ __launch_bounds__(256) void main_kernel(
        const float* __restrict__ latent, const void* __restrict__ maskp,
        const int* __restrict__ modep,
        const float* __restrict__ v, const float* __restrict__ c2,
        float* __restrict__ scores, float* __restrict__ partials) {
    int b = blockIdx.y, ch = blockIdx.x;
    int t = threadIdx.x, w = t >> 6, l = t & 63;
    int mode = *modep;
    float4 vv = ((const float4*)(v + b * D))[l];
    float c2b = c2[b];
    float ax = 0.f, ay = 0.f, az = 0.f, aw = 0.f;
    int n0 = ch * RPB + w * (RPB / 4);
    const float4* lat4 = (const float4*)(latent + (size_t)b * N * D);
    for (int i = 0; i < RPB / 4; ++i) {
        int n = n0 + i;
        float4 x = lat4[(size_t)n * (D / 4) + l];
        float p = x.x * vv.x;
        p = fmaf(x.y, vv.y, p);
        p = fmaf(x.z, vv.z, p);
        p = fmaf(x.w, vv.w, p);
        #pragma unroll
        for (int m = 32; m >= 1; m >>= 1) p += __shfl_xor(p, m, 64);
        bool msk = mask_at(maskp, mode, b * N + n);
        if (l == 0) scores[(size_t)b * N + n] = msk ? (p + c2b) : -INFINITY;
        if (msk) { ax += x.x; ay += x.y; az += x.z; aw += x.w; }
    }
    __shared__ float red[4][D];
    red[w][l * 4 + 0] = ax; red[w][l * 4 + 1] = ay;
    red[w][l * 4 + 2] = az; red[w][l * 4 + 3] = aw;
    __syncthreads();
    float s = red[0][t] + red[1][t] + red[2][t] + red[3][t];
    partials[((size_t)b * CH + ch) * D + t] = s;
}

// Fused epilogue per batch: radix-select top-K (parallel suffix-scan select)
// -> bitonic sort (jax ties) -> mask/softmax/index -> gather -> global_latent.
__global__ __launch_bounds__(256) void epilogue_kernel(
        const float* __restrict__ scores, const void* __restrict__ maskp,
        const int* __restrict__ modep, const float* __restrict__ latent,
        const float* __restrict__ partials, const float* __restrict__ cnt,
        float* __restrict__ out_mask, float* __restrict__ out_idx,
        float* __restrict__ out_imp, float* __restrict__ out_tok,
        float* __restrict__ out_glob) {
    int b = blockIdx.x, t = threadIdx.x, w = t >> 6, l = t & 63;
    __shared__ unsigned int keys[N];
    __shared__ unsigned int hist[256];
    __shared__ int wtot[4], wtot2[4];
    __shared__ unsigned int selu[K];
    __shared__ int seliA[K];
    __shared__ int sortedIdx[K];
    __shared__ unsigned int s_byte;
    __shared__ int s_kneed;

    // load + order-preserving float->uint map
    for (int i = 0; i < N / 256; ++i) {
        int pos = t + 256 * i;
        unsigned int fu = __float_as_uint(scores[(size_t)b * N + pos]);
        keys[pos] = (fu & 0x80000000u) ? ~fu : (fu | 0x80000000u);
    }
    __syncthreads();

    // 4-pass radix select with parallel suffix-scan bucket select
    unsigned int prefixKey = 0;
    int kneed = K;
    for (int shift = 24; shift >= 0; shift -= 8) {
        hist[t] = 0;
        __syncthreads();
        for (int i = 0; i < N / 256; ++i) {
            unsigned int u = keys[t * (N / 256) + i];
            bool match = (shift == 24) || ((u >> (shift + 8)) == (prefixKey >> (shift + 8)));
            if (match) atomicAdd(&hist[(u >> shift) & 0xFFu], 1u);
        }
        __syncthreads();
        // thread t owns bucket bb = 255 - t; inclusive from-top scan
        int h = (int)hist[255 - t];
        int incl = wave_iscan(h, l);
        if (l == 63) wtot[w] = incl;
        __syncthreads();
        int woff = 0;
        #pragma unroll
        for (int ww = 0; ww < 4; ++ww) if (ww < w) woff += wtot[ww];
        incl += woff;
        int excl = incl - h;
        if (incl >= kneed && excl < kneed) {
            s_byte = (unsigned int)(255 - t);
            s_kneed = kneed - excl;
        }
        __syncthreads();
        prefixKey |= (s_byte << shift);
        kneed = s_kneed;
        __syncthreads();
    }
    unsigned int T = prefixKey;

    // per-thread GT/EQ counts over contiguous chunk (index order preserved)
    int cGT = 0, cEQ = 0;
    for (int i = 0; i < N / 256; ++i) {
        unsigned int u = keys[t * (N / 256) + i];
        cGT += (u > T);
        cEQ += (u == T);
    }
    // block-wide exclusive prefix via shfl-scan + cross-wave combine
    int sGT = wave_iscan(cGT, l);
    int sEQ = wave_iscan(cEQ, l);
    if (l == 63) { wtot[w] = sGT; wtot2[w] = sEQ; }
    __syncthreads();
    int offGT = 0, offEQ = 0, totGT = 0;
    #pragma unroll
    for (int ww = 0; ww < 4; ++ww) {
        if (ww < w) { offGT += wtot[ww]; offEQ += wtot2[ww]; }
        totGT += wtot[ww];
    }
    int pg = sGT - cGT + offGT;      // exclusive prefixes
    int pe = sEQ - cEQ + offEQ;
    for (int i = 0; i < N / 256; ++i) {
        int pos = t * (N / 256) + i;
        unsigned int u = keys[pos];
        if (u > T) {
            selu[pg] = u; seliA[pg] = pos; ++pg;
        } else if (u == T) {
            if (pe < kneed) { selu[totGT + pe] = u; seliA[totGT + pe] = pos; }
            ++pe;
        }
    }
    __syncthreads();

    if (t < K) {
        unsigned int u = selu[t];
        int pos = seliA[t];
        // bitonic sort 64 pairs across wave 0, descending by (u, then -pos)
        #pragma unroll
        for (int k2 = 2; k2 <= 64; k2 <<= 1) {
            #pragma unroll
            for (int j = k2 >> 1; j >= 1; j >>= 1) {
                unsigned int ou = __shfl_xor(u, j, 64);
                int opos = __shfl_xor(pos, j, 64);
                bool lower = (t & j) == 0;
                bool descB = (t & k2) == 0;
                bool otherGreater = (ou > u) || (ou == u && opos < pos);
                if (otherGreater == (lower == descB)) { u = ou; pos = opos; }
            }
        }
        unsigned int fu = (u & 0x80000000u) ? (u ^ 0x80000000u) : ~u;
        float selv = __uint_as_float(fu);

        int mode = *modep;
        bool m = mask_at(maskp, mode, b * N + pos);
        float x = m ? selv : -1e9f;
        float mx = x;
        #pragma unroll
        for (int mm = 1; mm <= 32; mm <<= 1) mx = fmaxf(mx, __shfl_xor(mx, mm, 64));
        float e = expf(x - mx);
        float sm = e;
        #pragma unroll
        for (int mm = 1; mm <= 32; mm <<= 1) sm += __shfl_xor(sm, mm, 64);
        out_idx[b * K + t] = (float)pos;
        out_mask[b * K + t] = m ? 1.f : 0.f;
        out_imp[b * K + t] = e / sm;
        sortedIdx[t] = pos;
    }
    __syncthreads();

    // gather selected tokens (sorted order), 4 waves x 16 rows, float4 rows
    for (int r = w; r < K; r += 4) {
        int idx = sortedIdx[r];
        float4 x = ((const float4*)(latent + ((size_t)b * N + idx) * D))[l];
        ((float4*)(out_tok + ((size_t)b * K + r) * D))[l] = x;
    }
    // global_latent finalize
    float s = 0.f;
    for (int ch = 0; ch < CH; ++ch) s += partials[((size_t)b * CH + ch) * D + t];
    out_glob[b * D + t] = s / cnt[b];
}

extern "C" void kernel_launch(void* const* d_in, const int* in_sizes, int n_in,
                              void* d_out, int out_size, void* d_ws, size_t ws_size,
                              hipStream_t stream) {
    const float* latent = (const float*)d_in[0];
    const void*  maskp  = d_in[1];
    const float* Wq = (const float*)d_in[2];
    const float* bq = (const float*)d_in[3];
    const float* Wk = (const float*)d_in[4];
    const float* bk = (const float*)d_in[5];
    const float* Ws = (const float*)d_in[6];
    const float* bs = (const float*)d_in[7];

    float* ws = (float*)d_ws;
    float* v      = ws + OFF_V;
    float* c2     = ws + OFF_C2;
    float* cnt    = ws + OFF_CNT;
    float* scores = ws + OFF_SCORES;
    float* part   = ws + OFF_PART;
    int*   modep  = (int*)(ws + OFF_MODE);
    float* out = (float*)d_out;

    hipLaunchKernelGGL(prep_kernel, dim3(B), dim3(256), 0, stream,
                       latent, maskp, Wq, bq, Wk, bk, Ws, bs, v, c2, cnt, modep);
    hipLaunchKernelGGL(main_kernel, dim3(CH, B), dim3(256), 0, stream,
                       latent, maskp, modep, v, c2, scores, part);
    hipLaunchKernelGGL(epilogue_kernel, dim3(B), dim3(256), 0, stream,
                       scores, maskp, modep, latent, part, cnt,
                       out + O_MASK, out + O_IDX, out + O_IMP, out + O_TOK, out + O_GLOB);
}

// Round 5
// 116.082 us; speedup vs baseline: 1.3227x; 1.0258x over previous
//
#include <hip/hip_runtime.h>
#include <math.h>

#define B 128
#define N 2048
#define D 256
#define K 64
#define CH 16          // chunks per batch in main kernel
#define RPB (N / CH)   // rows per block = 128
#define MASKED_KEY 0x007FFFFFu   // = map(-inf); strictly below every finite-score key

// ---------------- workspace layout (in floats) ----------------
#define OFF_V       0                          // B*D = 32768
#define OFF_C2      (OFF_V + B * D)            // B
#define OFF_CNT     (OFF_C2 + B)               // B
#define OFF_KEYS    (OFF_CNT + B)              // B*N uints = 262144
#define OFF_PART    (OFF_KEYS + B * N)         // B*CH*D = 524288
#define OFF_MODE    (OFF_PART + B * CH * D)    // 1 int

// ---------------- output layout (in floats) ----------------
#define O_TOK   0                      // B*K*D = 2097152
#define O_MASK  (O_TOK + B * K * D)    // B*K
#define O_IDX   (O_MASK + B * K)       // B*K
#define O_IMP   (O_IDX + B * K)        // B*K
#define O_GLOB  (O_IMP + B * K)        // B*D

__device__ __forceinline__ bool mask_at(const void* p, int mode, int i) {
    if (mode == 1) return ((const unsigned char*)p)[i] != 0;
    if (mode == 2) return ((const float*)p)[i] != 0.0f;
    return ((const int*)p)[i] != 0;
}

// in-wave inclusive scan (64 lanes)
__device__ __forceinline__ int wave_iscan(int x, int l) {
    #pragma unroll
    for (int d = 1; d < 64; d <<= 1) {
        int y = __shfl_up(x, d, 64);
        if (l >= d) x += y;
    }
    return x;
}

// Per-batch: mode-detect; q = ego@Wq^T + bq (row-per-wave float4);
// v = (q^T Wk)/16 + Ws; c2 = (q.bk)/16 + bs; cnt = sum(mask).
__global__ __launch_bounds__(256) void prep_kernel(
        const float* __restrict__ latent, const void* __restrict__ maskp,
        const float* __restrict__ Wq, const float* __restrict__ bq,
        const float* __restrict__ Wk, const float* __restrict__ bk,
        const float* __restrict__ Ws, const float* __restrict__ bs,
        float* __restrict__ v, float* __restrict__ c2, float* __restrict__ cnt,
        int* __restrict__ modep) {
    int b = blockIdx.x, t = threadIdx.x, w = t >> 6, l = t & 63;
    __shared__ float ego[D];
    __shared__ float q[D];
    __shared__ int smode;
    if (w == 0) {
        const unsigned int* mw = (const unsigned int*)maskp;
        bool isF = false, hasHigh = false;
        for (int i = 0; i < 16; ++i) {
            unsigned int x = mw[l * 16 + i];
            if (x == 0x3F800000u) isF = true;
            if (x & 0xFFFFFF00u) hasHigh = true;
        }
        unsigned long long bf = __ballot(isF);
        unsigned long long bh = __ballot(hasHigh);
        if (l == 0) smode = bf ? 2 : (bh ? 1 : 0);
    }
    ego[t] = latent[(size_t)b * N * D + t];
    __syncthreads();
    int mode = smode;
    if (b == 0 && t == 0) *modep = mode;

    float4 e4 = ((const float4*)ego)[l];
    for (int r0 = 0; r0 < 64; ++r0) {
        int r = w * 64 + r0;
        float4 x = ((const float4*)(Wq + (size_t)r * D))[l];
        float p = x.x * e4.x;
        p = fmaf(x.y, e4.y, p);
        p = fmaf(x.z, e4.z, p);
        p = fmaf(x.w, e4.w, p);
        #pragma unroll
        for (int m = 32; m >= 1; m >>= 1) p += __shfl_xor(p, m, 64);
        if (l == 0) q[r] = p + bq[r];
    }
    __syncthreads();

    float a2 = 0.f;
    #pragma unroll 8
    for (int e = 0; e < D; ++e) a2 = fmaf(q[e], Wk[(size_t)e * D + t], a2);
    v[b * D + t] = a2 * 0.0625f + Ws[t];

    if (t < 64) {
        float p = 0.f;
        for (int j = 0; j < 4; ++j) { int e = t + 64 * j; p = fmaf(q[e], bk[e], p); }
        #pragma unroll
        for (int m = 32; m >= 1; m >>= 1) p += __shfl_xor(p, m, 64);
        if (t == 0) c2[b] = p * 0.0625f + bs[0];
    }
    int local = 0;
    for (int i = 0; i < N / D; ++i) local += mask_at(maskp, mode, b * N + t + D * i) ? 1 : 0;
    __shared__ int ctot;
    if (t == 0) ctot = 0;
    __syncthreads();
    atomicAdd(&ctot, local);
    __syncthreads();
    if (t == 0) cnt[b] = (float)ctot;
}

// Streaming pass: 16 lanes per row, 4 rows per wave-iteration.
// Writes order-preserving uint keys (masked -> MASKED_KEY) + partial column sums.
__global__ __launch_bounds__(256) void main_kernel(
        const float* __restrict__ latent, const void* __restrict__ maskp,
        const int* __restrict__ modep,
        const float* __restrict__ v, const float* __restrict__ c2,
        unsigned int* __restrict__ keys, float* __restrict__ partials) {
    int b = blockIdx.y, ch = blockIdx.x;
    int t = threadIdx.x, w = t >> 6, l = t & 63;
    int g = l >> 4, i = l & 15;
    int mode = *modep;
    const float4* v4 = (const float4*)(v + b * D);
    float4 vv0 = v4[i], vv1 = v4[i + 16], vv2 = v4[i + 32], vv3 = v4[i + 48];
    float c2b = c2[b];
    float4 a0 = {0,0,0,0}, a1 = {0,0,0,0}, a2 = {0,0,0,0}, a3 = {0,0,0,0};
    const float4* lat4 = (const float4*)(latent + (size_t)b * N * D);
    int n0 = ch * RPB + w * (RPB / 4);   // 32 rows per wave
    for (int it = 0; it < RPB / 16; ++it) {
        int n = n0 + it * 4 + g;
        const float4* row = lat4 + (size_t)n * (D / 4);
        float4 x0 = row[i], x1 = row[i + 16], x2 = row[i + 32], x3 = row[i + 48];
        float p = x0.x * vv0.x;
        p = fmaf(x0.y, vv0.y, p); p = fmaf(x0.z, vv0.z, p); p = fmaf(x0.w, vv0.w, p);
        p = fmaf(x1.x, vv1.x, p); p = fmaf(x1.y, vv1.y, p);
        p = fmaf(x1.z, vv1.z, p); p = fmaf(x1.w, vv1.w, p);
        p = fmaf(x2.x, vv2.x, p); p = fmaf(x2.y, vv2.y, p);
        p = fmaf(x2.z, vv2.z, p); p = fmaf(x2.w, vv2.w, p);
        p = fmaf(x3.x, vv3.x, p); p = fmaf(x3.y, vv3.y, p);
        p = fmaf(x3.z, vv3.z, p); p = fmaf(x3.w, vv3.w, p);
        #pragma unroll
        for (int m = 8; m >= 1; m >>= 1) p += __shfl_xor(p, m, 64);  // 16-lane group reduce
        bool msk = mask_at(maskp, mode, b * N + n);
        if (i == 0) {
            unsigned int ky = MASKED_KEY;
            if (msk) {
                unsigned int fu = __float_as_uint(p + c2b);
                ky = (fu & 0x80000000u) ? ~fu : (fu | 0x80000000u);
            }
            keys[(size_t)b * N + n] = ky;
        }
        if (msk) {
            a0.x += x0.x; a0.y += x0.y; a0.z += x0.z; a0.w += x0.w;
            a1.x += x1.x; a1.y += x1.y; a1.z += x1.z; a1.w += x1.w;
            a2.x += x2.x; a2.y += x2.y; a2.z += x2.z; a2.w += x2.w;
            a3.x += x3.x; a3.y += x3.y; a3.z += x3.z; a3.w += x3.w;
        }
    }
    __shared__ float red[16][D];
    float4* rr = (float4*)red[w * 4 + g];
    rr[i] = a0; rr[i + 16] = a1; rr[i + 32] = a2; rr[i + 48] = a3;
    __syncthreads();
    float s = 0.f;
    #pragma unroll
    for (int r = 0; r < 16; ++r) s += red[r][t];
    partials[((size_t)b * CH + ch) * D + t] = s;
}

// Fused epilogue per batch: radix-select top-K over precomputed keys ->
// bitonic sort (jax ties) -> mask/softmax/index -> gather -> global_latent.
__global__ __launch_bounds__(256) void epilogue_kernel(
        const unsigned int* __restrict__ keysg, const float* __restrict__ latent,
        const float* __restrict__ partials, const float* __restrict__ cnt,
        float* __restrict__ out_mask, float* __restrict__ out_idx,
        float* __restrict__ out_imp, float* __restrict__ out_tok,
        float* __restrict__ out_glob) {
    int b = blockIdx.x, t = threadIdx.x, w = t >> 6, l = t & 63;
    __shared__ unsigned int keys[N];
    __shared__ unsigned int hist[256];
    __shared__ int wtot[4], wtot2[4];
    __shared__ unsigned int selu[K];
    __shared__ int seliA[K];
    __shared__ int sortedIdx[K];
    __shared__ unsigned int s_byte;
    __shared__ int s_kneed;

    for (int i = 0; i < N / 256; ++i) {
        int pos = t + 256 * i;
        keys[pos] = keysg[(size_t)b * N + pos];
    }
    __syncthreads();

    // 4-pass radix select with parallel suffix-scan bucket select
    unsigned int prefixKey = 0;
    int kneed = K;
    for (int shift = 24; shift >= 0; shift -= 8) {
        hist[t] = 0;
        __syncthreads();
        for (int i = 0; i < N / 256; ++i) {
            unsigned int u = keys[t * (N / 256) + i];
            bool match = (shift == 24) || ((u >> (shift + 8)) == (prefixKey >> (shift + 8)));
            if (match) atomicAdd(&hist[(u >> shift) & 0xFFu], 1u);
        }
        __syncthreads();
        // thread t owns bucket 255 - t; inclusive from-top scan
        int h = (int)hist[255 - t];
        int incl = wave_iscan(h, l);
        if (l == 63) wtot[w] = incl;
        __syncthreads();
        int woff = 0;
        #pragma unroll
        for (int ww = 0; ww < 4; ++ww) if (ww < w) woff += wtot[ww];
        incl += woff;
        int excl = incl - h;
        if (incl >= kneed && excl < kneed) {
            s_byte = (unsigned int)(255 - t);
            s_kneed = kneed - excl;
        }
        __syncthreads();
        prefixKey |= (s_byte << shift);
        kneed = s_kneed;
        __syncthreads();
    }
    unsigned int T = prefixKey;

    // per-thread GT/EQ counts over contiguous chunk (index order preserved)
    int cGT = 0, cEQ = 0;
    for (int i = 0; i < N / 256; ++i) {
        unsigned int u = keys[t * (N / 256) + i];
        cGT += (u > T);
        cEQ += (u == T);
    }
    int sGT = wave_iscan(cGT, l);
    int sEQ = wave_iscan(cEQ, l);
    if (l == 63) { wtot[w] = sGT; wtot2[w] = sEQ; }
    __syncthreads();
    int offGT = 0, offEQ = 0, totGT = 0;
    #pragma unroll
    for (int ww = 0; ww < 4; ++ww) {
        if (ww < w) { offGT += wtot[ww]; offEQ += wtot2[ww]; }
        totGT += wtot[ww];
    }
    int pg = sGT - cGT + offGT;
    int pe = sEQ - cEQ + offEQ;
    for (int i = 0; i < N / 256; ++i) {
        int pos = t * (N / 256) + i;
        unsigned int u = keys[pos];
        if (u > T) {
            selu[pg] = u; seliA[pg] = pos; ++pg;
        } else if (u == T) {
            if (pe < kneed) { selu[totGT + pe] = u; seliA[totGT + pe] = pos; }
            ++pe;
        }
    }
    __syncthreads();

    if (t < K) {
        unsigned int u = selu[t];
        int pos = seliA[t];
        // bitonic sort 64 pairs across wave 0, descending by (u, then -pos)
        #pragma unroll
        for (int k2 = 2; k2 <= 64; k2 <<= 1) {
            #pragma unroll
            for (int j = k2 >> 1; j >= 1; j >>= 1) {
                unsigned int ou = __shfl_xor(u, j, 64);
                int opos = __shfl_xor(pos, j, 64);
                bool lower = (t & j) == 0;
                bool descB = (t & k2) == 0;
                bool otherGreater = (ou > u) || (ou == u && opos < pos);
                if (otherGreater == (lower == descB)) { u = ou; pos = opos; }
            }
        }
        unsigned int fu = (u & 0x80000000u) ? (u ^ 0x80000000u) : ~u;
        float selv = __uint_as_float(fu);

        bool m = (u != MASKED_KEY);
        float x = m ? selv : -1e9f;
        float mx = x;
        #pragma unroll
        for (int mm = 1; mm <= 32; mm <<= 1) mx = fmaxf(mx, __shfl_xor(mx, mm, 64));
        float e = expf(x - mx);
        float sm = e;
        #pragma unroll
        for (int mm = 1; mm <= 32; mm <<= 1) sm += __shfl_xor(sm, mm, 64);
        out_idx[b * K + t] = (float)pos;
        out_mask[b * K + t] = m ? 1.f : 0.f;
        out_imp[b * K + t] = e / sm;
        sortedIdx[t] = pos;
    }
    __syncthreads();

    for (int r = w; r < K; r += 4) {
        int idx = sortedIdx[r];
        float4 x = ((const float4*)(latent + ((size_t)b * N + idx) * D))[l];
        ((float4*)(out_tok + ((size_t)b * K + r) * D))[l] = x;
    }
    float s = 0.f;
    for (int ch = 0; ch < CH; ++ch) s += partials[((size_t)b * CH + ch) * D + t];
    out_glob[b * D + t] = s / cnt[b];
}

extern "C" void kernel_launch(void* const* d_in, const int* in_sizes, int n_in,
                              void* d_out, int out_size, void* d_ws, size_t ws_size,
                              hipStream_t stream) {
    const float* latent = (const float*)d_in[0];
    const void*  maskp  = d_in[1];
    const float* Wq = (const float*)d_in[2];
    const float* bq = (const float*)d_in[3];
    const float* Wk = (const float*)d_in[4];
    const float* bk = (const float*)d_in[5];
    const float* Ws = (const float*)d_in[6];
    const float* bs = (const float*)d_in[7];

    float* ws = (float*)d_ws;
    float* v      = ws + OFF_V;
    float* c2     = ws + OFF_C2;
    float* cnt    = ws + OFF_CNT;
    unsigned int* keys = (unsigned int*)(ws + OFF_KEYS);
    float* part   = ws + OFF_PART;
    int*   modep  = (int*)(ws + OFF_MODE);
    float* out = (float*)d_out;

    hipLaunchKernelGGL(prep_kernel, dim3(B), dim3(256), 0, stream,
                       latent, maskp, Wq, bq, Wk, bk, Ws, bs, v, c2, cnt, modep);
    hipLaunchKernelGGL(main_kernel, dim3(CH, B), dim3(256), 0, stream,
                       latent, maskp, modep, v, c2, keys, part);
    hipLaunchKernelGGL(epilogue_kernel, dim3(B), dim3(256), 0, stream,
                       keys, latent, part, cnt,
                       out + O_MASK, out + O_IDX, out + O_IMP, out + O_TOK, out + O_GLOB);
}

// Round 6
// 100.221 us; speedup vs baseline: 1.5320x; 1.1583x over previous
//
#include <hip/hip_runtime.h>
#include <math.h>

#define B 128
#define N 2048
#define D 256
#define K 64
#define CH 16          // chunks per batch in main kernel
#define RPB (N / CH)   // rows per block = 128
#define MASKED_KEY 0x007FFFFFu   // = map(-inf); strictly below every finite-score key

// ---------------- workspace layout (in floats) ----------------
#define OFF_V       0                          // B*D = 32768
#define OFF_C2      (OFF_V + B * D)            // B
#define OFF_CNT     (OFF_C2 + B)               // B
#define OFF_KEYS    (OFF_CNT + B)              // B*N uints = 262144
#define OFF_PART    (OFF_KEYS + B * N)         // B*CH*D = 524288
#define OFF_MODE    (OFF_PART + B * CH * D)    // 1 int
#define OFF_MHAT    (OFF_MODE + 64)            // D*D = 65536 (aligned)
#define OFF_U0      (OFF_MHAT + D * D)         // D
#define OFF_W2      (OFF_U0 + D)               // D
#define OFF_CST2    (OFF_W2 + D)               // 1

// ---------------- output layout (in floats) ----------------
#define O_TOK   0                      // B*K*D = 2097152
#define O_MASK  (O_TOK + B * K * D)    // B*K
#define O_IDX   (O_MASK + B * K)       // B*K
#define O_IMP   (O_IDX + B * K)        // B*K
#define O_GLOB  (O_IMP + B * K)        // B*D

__device__ __forceinline__ bool mask_at(const void* p, int mode, int i) {
    if (mode == 1) return ((const unsigned char*)p)[i] != 0;
    if (mode == 2) return ((const float*)p)[i] != 0.0f;
    return ((const int*)p)[i] != 0;
}

// in-wave inclusive scan (64 lanes)
__device__ __forceinline__ int wave_iscan(int x, int l) {
    #pragma unroll
    for (int d = 1; d < 64; d <<= 1) {
        int y = __shfl_up(x, d, 64);
        if (l >= d) x += y;
    }
    return x;
}

// Batch-independent fold: Mhat = (Wq^T Wk)/16, u0 = (bq^T Wk)/16 + Ws,
// w2 = (Wq^T bk)/16, cst2 = (bq.bk)/16 + bs.  Block e in [0,256]: e<256 ->
// column e of Wq; e==256 -> bq.
__global__ __launch_bounds__(256) void prep0_kernel(
        const float* __restrict__ Wq, const float* __restrict__ bq,
        const float* __restrict__ Wk, const float* __restrict__ bk,
        const float* __restrict__ Ws, const float* __restrict__ bs,
        float* __restrict__ Mhat, float* __restrict__ u0,
        float* __restrict__ w2, float* __restrict__ cst2) {
    int e = blockIdx.x, t = threadIdx.x;
    __shared__ float col[D];
    col[t] = (e < D) ? Wq[(size_t)t * D + e] : bq[t];
    __syncthreads();
    float acc = 0.f;
    #pragma unroll 8
    for (int r = 0; r < D; ++r) acc = fmaf(col[r], Wk[(size_t)r * D + t], acc);
    if (e < D) Mhat[(size_t)e * D + t] = acc * 0.0625f;
    else       u0[t] = acc * 0.0625f + Ws[t];
    if (t < 64) {
        float p = 0.f;
        #pragma unroll
        for (int j = 0; j < 4; ++j) p = fmaf(col[t + 64 * j], bk[t + 64 * j], p);
        #pragma unroll
        for (int m = 32; m >= 1; m >>= 1) p += __shfl_xor(p, m, 64);
        if (t == 0) {
            if (e < D) w2[e] = p * 0.0625f;
            else       cst2[0] = p * 0.0625f + bs[0];
        }
    }
}

// Per-batch: mode-detect; v_b = ego_b @ Mhat + u0 (single coalesced sweep);
// c2_b = ego_b . w2 + cst2; cnt = sum(mask).
__global__ __launch_bounds__(256) void prep1_kernel(
        const float* __restrict__ latent, const void* __restrict__ maskp,
        const float* __restrict__ Mhat, const float* __restrict__ u0,
        const float* __restrict__ w2, const float* __restrict__ cst2,
        float* __restrict__ v, float* __restrict__ c2, float* __restrict__ cnt,
        int* __restrict__ modep) {
    int b = blockIdx.x, t = threadIdx.x, w = t >> 6, l = t & 63;
    __shared__ float ego[D];
    __shared__ int smode;
    if (w == 0) {
        const unsigned int* mw = (const unsigned int*)maskp;
        bool isF = false, hasHigh = false;
        for (int i = 0; i < 16; ++i) {
            unsigned int x = mw[l * 16 + i];
            if (x == 0x3F800000u) isF = true;
            if (x & 0xFFFFFF00u) hasHigh = true;
        }
        unsigned long long bf = __ballot(isF);
        unsigned long long bh = __ballot(hasHigh);
        if (l == 0) smode = bf ? 2 : (bh ? 1 : 0);
    }
    ego[t] = latent[(size_t)b * N * D + t];
    __syncthreads();
    int mode = smode;
    if (b == 0 && t == 0) *modep = mode;

    float acc = 0.f;
    #pragma unroll 8
    for (int e = 0; e < D; ++e) acc = fmaf(ego[e], Mhat[(size_t)e * D + t], acc);
    v[b * D + t] = acc + u0[t];

    if (t < 64) {
        float p = 0.f;
        #pragma unroll
        for (int j = 0; j < 4; ++j) p = fmaf(ego[t + 64 * j], w2[t + 64 * j], p);
        #pragma unroll
        for (int m = 32; m >= 1; m >>= 1) p += __shfl_xor(p, m, 64);
        if (t == 0) c2[b] = p + cst2[0];
    }
    int local = 0;
    for (int i = 0; i < N / D; ++i) local += mask_at(maskp, mode, b * N + t + D * i) ? 1 : 0;
    __shared__ int ctot;
    if (t == 0) ctot = 0;
    __syncthreads();
    atomicAdd(&ctot, local);
    __syncthreads();
    if (t == 0) cnt[b] = (float)ctot;
}

// Streaming pass: 16 lanes per row, 4 rows per wave-iteration.
// Writes order-preserving uint keys (masked -> MASKED_KEY) + partial column sums.
__global__ __launch_bounds__(256) void main_kernel(
        const float* __restrict__ latent, const void* __restrict__ maskp,
        const int* __restrict__ modep,
        const float* __restrict__ v, const float* __restrict__ c2,
        unsigned int* __restrict__ keys, float* __restrict__ partials) {
    int b = blockIdx.y, ch = blockIdx.x;
    int t = threadIdx.x, w = t >> 6, l = t & 63;
    int g = l >> 4, i = l & 15;
    int mode = *modep;
    const float4* v4 = (const float4*)(v + b * D);
    float4 vv0 = v4[i], vv1 = v4[i + 16], vv2 = v4[i + 32], vv3 = v4[i + 48];
    float c2b = c2[b];
    float4 a0 = {0,0,0,0}, a1 = {0,0,0,0}, a2 = {0,0,0,0}, a3 = {0,0,0,0};
    const float4* lat4 = (const float4*)(latent + (size_t)b * N * D);
    int n0 = ch * RPB + w * (RPB / 4);   // 32 rows per wave
    for (int it = 0; it < RPB / 16; ++it) {
        int n = n0 + it * 4 + g;
        const float4* row = lat4 + (size_t)n * (D / 4);
        float4 x0 = row[i], x1 = row[i + 16], x2 = row[i + 32], x3 = row[i + 48];
        float p = x0.x * vv0.x;
        p = fmaf(x0.y, vv0.y, p); p = fmaf(x0.z, vv0.z, p); p = fmaf(x0.w, vv0.w, p);
        p = fmaf(x1.x, vv1.x, p); p = fmaf(x1.y, vv1.y, p);
        p = fmaf(x1.z, vv1.z, p); p = fmaf(x1.w, vv1.w, p);
        p = fmaf(x2.x, vv2.x, p); p = fmaf(x2.y, vv2.y, p);
        p = fmaf(x2.z, vv2.z, p); p = fmaf(x2.w, vv2.w, p);
        p = fmaf(x3.x, vv3.x, p); p = fmaf(x3.y, vv3.y, p);
        p = fmaf(x3.z, vv3.z, p); p = fmaf(x3.w, vv3.w, p);
        #pragma unroll
        for (int m = 8; m >= 1; m >>= 1) p += __shfl_xor(p, m, 64);  // 16-lane group reduce
        bool msk = mask_at(maskp, mode, b * N + n);
        if (i == 0) {
            unsigned int ky = MASKED_KEY;
            if (msk) {
                unsigned int fu = __float_as_uint(p + c2b);
                ky = (fu & 0x80000000u) ? ~fu : (fu | 0x80000000u);
            }
            keys[(size_t)b * N + n] = ky;
        }
        if (msk) {
            a0.x += x0.x; a0.y += x0.y; a0.z += x0.z; a0.w += x0.w;
            a1.x += x1.x; a1.y += x1.y; a1.z += x1.z; a1.w += x1.w;
            a2.x += x2.x; a2.y += x2.y; a2.z += x2.z; a2.w += x2.w;
            a3.x += x3.x; a3.y += x3.y; a3.z += x3.z; a3.w += x3.w;
        }
    }
    __shared__ float red[16][D];
    float4* rr = (float4*)red[w * 4 + g];
    rr[i] = a0; rr[i + 16] = a1; rr[i + 32] = a2; rr[i + 48] = a3;
    __syncthreads();
    float s = 0.f;
    #pragma unroll
    for (int r = 0; r < 16; ++r) s += red[r][t];
    partials[((size_t)b * CH + ch) * D + t] = s;
}

// Fused epilogue per batch: radix-select top-K over precomputed keys ->
// bitonic sort (jax ties) -> mask/softmax/index -> gather -> global_latent.
__global__ __launch_bounds__(256) void epilogue_kernel(
        const unsigned int* __restrict__ keysg, const float* __restrict__ latent,
        const float* __restrict__ partials, const float* __restrict__ cnt,
        float* __restrict__ out_mask, float* __restrict__ out_idx,
        float* __restrict__ out_imp, float* __restrict__ out_tok,
        float* __restrict__ out_glob) {
    int b = blockIdx.x, t = threadIdx.x, w = t >> 6, l = t & 63;
    __shared__ unsigned int keys[N];
    __shared__ unsigned int hist[256];
    __shared__ int wtot[4], wtot2[4];
    __shared__ unsigned int selu[K];
    __shared__ int seliA[K];
    __shared__ int sortedIdx[K];
    __shared__ unsigned int s_byte;
    __shared__ int s_kneed;

    for (int i = 0; i < N / 256; ++i) {
        int pos = t + 256 * i;
        keys[pos] = keysg[(size_t)b * N + pos];
    }
    __syncthreads();

    // 4-pass radix select with parallel suffix-scan bucket select
    unsigned int prefixKey = 0;
    int kneed = K;
    for (int shift = 24; shift >= 0; shift -= 8) {
        hist[t] = 0;
        __syncthreads();
        for (int i = 0; i < N / 256; ++i) {
            unsigned int u = keys[t * (N / 256) + i];
            bool match = (shift == 24) || ((u >> (shift + 8)) == (prefixKey >> (shift + 8)));
            if (match) atomicAdd(&hist[(u >> shift) & 0xFFu], 1u);
        }
        __syncthreads();
        // thread t owns bucket 255 - t; inclusive from-top scan
        int h = (int)hist[255 - t];
        int incl = wave_iscan(h, l);
        if (l == 63) wtot[w] = incl;
        __syncthreads();
        int woff = 0;
        #pragma unroll
        for (int ww = 0; ww < 4; ++ww) if (ww < w) woff += wtot[ww];
        incl += woff;
        int excl = incl - h;
        if (incl >= kneed && excl < kneed) {
            s_byte = (unsigned int)(255 - t);
            s_kneed = kneed - excl;
        }
        __syncthreads();
        prefixKey |= (s_byte << shift);
        kneed = s_kneed;
        __syncthreads();
    }
    unsigned int T = prefixKey;

    // per-thread GT/EQ counts over contiguous chunk (index order preserved)
    int cGT = 0, cEQ = 0;
    for (int i = 0; i < N / 256; ++i) {
        unsigned int u = keys[t * (N / 256) + i];
        cGT += (u > T);
        cEQ += (u == T);
    }
    int sGT = wave_iscan(cGT, l);
    int sEQ = wave_iscan(cEQ, l);
    if (l == 63) { wtot[w] = sGT; wtot2[w] = sEQ; }
    __syncthreads();
    int offGT = 0, offEQ = 0, totGT = 0;
    #pragma unroll
    for (int ww = 0; ww < 4; ++ww) {
        if (ww < w) { offGT += wtot[ww]; offEQ += wtot2[ww]; }
        totGT += wtot[ww];
    }
    int pg = sGT - cGT + offGT;
    int pe = sEQ - cEQ + offEQ;
    for (int i = 0; i < N / 256; ++i) {
        int pos = t * (N / 256) + i;
        unsigned int u = keys[pos];
        if (u > T) {
            selu[pg] = u; seliA[pg] = pos; ++pg;
        } else if (u == T) {
            if (pe < kneed) { selu[totGT + pe] = u; seliA[totGT + pe] = pos; }
            ++pe;
        }
    }
    __syncthreads();

    if (t < K) {
        unsigned int u = selu[t];
        int pos = seliA[t];
        // bitonic sort 64 pairs across wave 0, descending by (u, then -pos)
        #pragma unroll
        for (int k2 = 2; k2 <= 64; k2 <<= 1) {
            #pragma unroll
            for (int j = k2 >> 1; j >= 1; j >>= 1) {
                unsigned int ou = __shfl_xor(u, j, 64);
                int opos = __shfl_xor(pos, j, 64);
                bool lower = (t & j) == 0;
                bool descB = (t & k2) == 0;
                bool otherGreater = (ou > u) || (ou == u && opos < pos);
                if (otherGreater == (lower == descB)) { u = ou; pos = opos; }
            }
        }
        unsigned int fu = (u & 0x80000000u) ? (u ^ 0x80000000u) : ~u;
        float selv = __uint_as_float(fu);

        bool m = (u != MASKED_KEY);
        float x = m ? selv : -1e9f;
        float mx = x;
        #pragma unroll
        for (int mm = 1; mm <= 32; mm <<= 1) mx = fmaxf(mx, __shfl_xor(mx, mm, 64));
        float e = expf(x - mx);
        float sm = e;
        #pragma unroll
        for (int mm = 1; mm <= 32; mm <<= 1) sm += __shfl_xor(sm, mm, 64);
        out_idx[b * K + t] = (float)pos;
        out_mask[b * K + t] = m ? 1.f : 0.f;
        out_imp[b * K + t] = e / sm;
        sortedIdx[t] = pos;
    }
    __syncthreads();

    for (int r = w; r < K; r += 4) {
        int idx = sortedIdx[r];
        float4 x = ((const float4*)(latent + ((size_t)b * N + idx) * D))[l];
        ((float4*)(out_tok + ((size_t)b * K + r) * D))[l] = x;
    }
    float s = 0.f;
    for (int ch = 0; ch < CH; ++ch) s += partials[((size_t)b * CH + ch) * D + t];
    out_glob[b * D + t] = s / cnt[b];
}

extern "C" void kernel_launch(void* const* d_in, const int* in_sizes, int n_in,
                              void* d_out, int out_size, void* d_ws, size_t ws_size,
                              hipStream_t stream) {
    const float* latent = (const float*)d_in[0];
    const void*  maskp  = d_in[1];
    const float* Wq = (const float*)d_in[2];
    const float* bq = (const float*)d_in[3];
    const float* Wk = (const float*)d_in[4];
    const float* bk = (const float*)d_in[5];
    const float* Ws = (const float*)d_in[6];
    const float* bs = (const float*)d_in[7];

    float* ws = (float*)d_ws;
    float* v      = ws + OFF_V;
    float* c2     = ws + OFF_C2;
    float* cnt    = ws + OFF_CNT;
    unsigned int* keys = (unsigned int*)(ws + OFF_KEYS);
    float* part   = ws + OFF_PART;
    int*   modep  = (int*)(ws + OFF_MODE);
    float* Mhat   = ws + OFF_MHAT;
    float* u0     = ws + OFF_U0;
    float* w2     = ws + OFF_W2;
    float* cst2   = ws + OFF_CST2;
    float* out = (float*)d_out;

    hipLaunchKernelGGL(prep0_kernel, dim3(D + 1), dim3(256), 0, stream,
                       Wq, bq, Wk, bk, Ws, bs, Mhat, u0, w2, cst2);
    hipLaunchKernelGGL(prep1_kernel, dim3(B), dim3(256), 0, stream,
                       latent, maskp, Mhat, u0, w2, cst2, v, c2, cnt, modep);
    hipLaunchKernelGGL(main_kernel, dim3(CH, B), dim3(256), 0, stream,
                       latent, maskp, modep, v, c2, keys, part);
    hipLaunchKernelGGL(epilogue_kernel, dim3(B), dim3(256), 0, stream,
                       keys, latent, part, cnt,
                       out + O_MASK, out + O_IDX, out + O_IMP, out + O_TOK, out + O_GLOB);
}